// Round 7
// baseline (4153.862 us; speedup 1.0000x reference)
//
#include <hip/hip_runtime.h>

// Problem constants
// B=2, T=2048, C=1024, H=16, D=64, MAXREL=32
// outputs: y [B,T,C] then att [B,H,T,T], both f32, concatenated in d_out.

typedef __bf16 bf16x8 __attribute__((ext_vector_type(8)));
typedef float f32x4 __attribute__((ext_vector_type(4)));
typedef unsigned short u16x8 __attribute__((ext_vector_type(8)));

__device__ __forceinline__ unsigned short f2bf(float f) {
  unsigned u = __float_as_uint(f);
  u += 0x7fff + ((u >> 16) & 1);
  return (unsigned short)(u >> 16);
}
__device__ __forceinline__ float bf2f(unsigned short s) {
  return __uint_as_float(((unsigned)s) << 16);
}

// ---------------------------------------------------------------------------
// cvt_split: f32[n] -> hi bf16[n], lo bf16[n]
// ---------------------------------------------------------------------------
__global__ __launch_bounds__(256)
void cvt_split(const float* __restrict__ in, unsigned short* __restrict__ hi,
               unsigned short* __restrict__ lo, int n4) {
  int i = blockIdx.x * 256 + threadIdx.x;
  if (i >= n4) return;
  float4 v = ((const float4*)in)[i];
  ushort4 h, l;
  h.x = f2bf(v.x); l.x = f2bf(v.x - bf2f(h.x));
  h.y = f2bf(v.y); l.y = f2bf(v.y - bf2f(h.y));
  h.z = f2bf(v.z); l.z = f2bf(v.z - bf2f(h.z));
  h.w = f2bf(v.w); l.w = f2bf(v.w - bf2f(h.w));
  ((ushort4*)hi)[i] = h;
  ((ushort4*)lo)[i] = l;
}

// ---------------------------------------------------------------------------
// cvt_split_T: in f32[K][N] -> hiT,loT bf16[N][K]
// ---------------------------------------------------------------------------
__global__ __launch_bounds__(256)
void cvt_split_T(const float* __restrict__ in, unsigned short* __restrict__ hiT,
                 unsigned short* __restrict__ loT, int K, int N) {
  __shared__ float tile[64][65];
  const int tid = threadIdx.x;
  const int bc = blockIdx.x * 64;  // n block
  const int br = blockIdx.y * 64;  // k block
#pragma unroll
  for (int j = 0; j < 4; ++j) {
    int f = tid + j * 256;
    int r = f >> 4, c4 = (f & 15) << 2;
    *(float4*)&tile[r][c4] = *(const float4*)&in[(size_t)(br + r) * N + bc + c4];
  }
  __syncthreads();
#pragma unroll
  for (int j = 0; j < 4; ++j) {
    int f = tid + j * 256;
    int n = f >> 4, k4 = (f & 15) << 2;
    ushort4 h, l;
    float v;
    v = tile[k4 + 0][n]; h.x = f2bf(v); l.x = f2bf(v - bf2f(h.x));
    v = tile[k4 + 1][n]; h.y = f2bf(v); l.y = f2bf(v - bf2f(h.y));
    v = tile[k4 + 2][n]; h.z = f2bf(v); l.z = f2bf(v - bf2f(h.z));
    v = tile[k4 + 3][n]; h.w = f2bf(v); l.w = f2bf(v - bf2f(h.w));
    size_t o = (size_t)(bc + n) * K + br + k4;
    *(ushort4*)&hiT[o] = h;
    *(ushort4*)&loT[o] = l;
  }
}

// ---------------------------------------------------------------------------
// Split-bf16 MFMA GEMM (unchanged from round 6 — verified)
// ---------------------------------------------------------------------------
__device__ __forceinline__ int swz(int row, int k) {
  return row * 32 + ((((k >> 3) ^ row) & 3) << 3) + (k & 7);
}

__global__ __launch_bounds__(256)
void mfma_gemm_bias(const unsigned short* __restrict__ Ah,
                    const unsigned short* __restrict__ Al,
                    const unsigned short* __restrict__ Bth,
                    const unsigned short* __restrict__ Btl,
                    const float* __restrict__ bias, float* __restrict__ C,
                    int M, int N, int K) {
  __shared__ unsigned short As_h[128 * 32], As_l[128 * 32];
  __shared__ unsigned short Bs_h[128 * 32], Bs_l[128 * 32];
  const int tid = threadIdx.x;
  const int bm = blockIdx.y * 128, bn = blockIdx.x * 128;
  const int l = tid & 63, w = tid >> 6;
  const int wm = (w >> 1) * 64, wn = (w & 1) * 64;
  const int fr = l & 15, kg = (l >> 4) << 3;

  const int u0 = tid, u1 = tid + 256;
  const int m0s = u0 >> 2, k0s = (u0 & 3) << 3;
  const int m1s = u1 >> 2, k1s = (u1 & 3) << 3;

  f32x4 acc[4][4];
#pragma unroll
  for (int i = 0; i < 4; ++i)
#pragma unroll
    for (int j = 0; j < 4; ++j) {
      acc[i][j].x = 0.f; acc[i][j].y = 0.f; acc[i][j].z = 0.f; acc[i][j].w = 0.f;
    }

  u16x8 rah0, rah1, ral0, ral1, rbh0, rbh1, rbl0, rbl1;
  {
    const size_t a0 = (size_t)(bm + m0s) * K + k0s, a1 = (size_t)(bm + m1s) * K + k1s;
    const size_t b0 = (size_t)(bn + m0s) * K + k0s, b1 = (size_t)(bn + m1s) * K + k1s;
    rah0 = *(const u16x8*)&Ah[a0];  rah1 = *(const u16x8*)&Ah[a1];
    ral0 = *(const u16x8*)&Al[a0];  ral1 = *(const u16x8*)&Al[a1];
    rbh0 = *(const u16x8*)&Bth[b0]; rbh1 = *(const u16x8*)&Bth[b1];
    rbl0 = *(const u16x8*)&Btl[b0]; rbl1 = *(const u16x8*)&Btl[b1];
  }

  const int nk = K >> 5;
  for (int ks = 0; ks < nk; ++ks) {
    __syncthreads();
    *(u16x8*)&As_h[swz(m0s, k0s)] = rah0;  *(u16x8*)&As_h[swz(m1s, k1s)] = rah1;
    *(u16x8*)&As_l[swz(m0s, k0s)] = ral0;  *(u16x8*)&As_l[swz(m1s, k1s)] = ral1;
    *(u16x8*)&Bs_h[swz(m0s, k0s)] = rbh0;  *(u16x8*)&Bs_h[swz(m1s, k1s)] = rbh1;
    *(u16x8*)&Bs_l[swz(m0s, k0s)] = rbl0;  *(u16x8*)&Bs_l[swz(m1s, k1s)] = rbl1;
    __syncthreads();
    if (ks + 1 < nk) {
      const int k0 = (ks + 1) << 5;
      const size_t a0 = (size_t)(bm + m0s) * K + k0 + k0s,
                   a1 = (size_t)(bm + m1s) * K + k0 + k1s;
      const size_t b0 = (size_t)(bn + m0s) * K + k0 + k0s,
                   b1 = (size_t)(bn + m1s) * K + k0 + k1s;
      rah0 = *(const u16x8*)&Ah[a0];  rah1 = *(const u16x8*)&Ah[a1];
      ral0 = *(const u16x8*)&Al[a0];  ral1 = *(const u16x8*)&Al[a1];
      rbh0 = *(const u16x8*)&Bth[b0]; rbh1 = *(const u16x8*)&Bth[b1];
      rbl0 = *(const u16x8*)&Btl[b0]; rbl1 = *(const u16x8*)&Btl[b1];
    }
    bf16x8 ah[4], al[4], bh[4], bl[4];
#pragma unroll
    for (int i = 0; i < 4; ++i) {
      ah[i] = *(bf16x8*)&As_h[swz(wm + i * 16 + fr, kg)];
      al[i] = *(bf16x8*)&As_l[swz(wm + i * 16 + fr, kg)];
      bh[i] = *(bf16x8*)&Bs_h[swz(wn + i * 16 + fr, kg)];
      bl[i] = *(bf16x8*)&Bs_l[swz(wn + i * 16 + fr, kg)];
    }
#pragma unroll
    for (int mi = 0; mi < 4; ++mi)
#pragma unroll
      for (int ni = 0; ni < 4; ++ni) {
        acc[mi][ni] = __builtin_amdgcn_mfma_f32_16x16x32_bf16(
            ah[mi], bh[ni], acc[mi][ni], 0, 0, 0);
        acc[mi][ni] = __builtin_amdgcn_mfma_f32_16x16x32_bf16(
            ah[mi], bl[ni], acc[mi][ni], 0, 0, 0);
        acc[mi][ni] = __builtin_amdgcn_mfma_f32_16x16x32_bf16(
            al[mi], bh[ni], acc[mi][ni], 0, 0, 0);
      }
  }

#pragma unroll
  for (int mi = 0; mi < 4; ++mi) {
    const int rowb = bm + wm + mi * 16 + (l >> 4) * 4;
#pragma unroll
    for (int ni = 0; ni < 4; ++ni) {
      const int col = bn + wn + ni * 16 + fr;
      const float bv = bias[col];
      C[(size_t)(rowb + 0) * N + col] = acc[mi][ni].x + bv;
      C[(size_t)(rowb + 1) * N + col] = acc[mi][ni].y + bv;
      C[(size_t)(rowb + 2) * N + col] = acc[mi][ni].z + bv;
      C[(size_t)(rowb + 3) * N + col] = acc[mi][ni].w + bv;
    }
  }
}

// ---------------------------------------------------------------------------
// proj[b,h,q,r] = sum_d q[b,h,q,d] * rel_k_table[r,d]   (unchanged)
// ---------------------------------------------------------------------------
__global__ __launch_bounds__(256)
void relproj_kernel(const float* __restrict__ qkv, const float* __restrict__ tbl_g,
                    float* __restrict__ proj) {
  __shared__ float tbl[65 * 65];
  __shared__ float qsh[4 * 64];
  const int tid = threadIdx.x;
  for (int i = tid; i < 65 * 64; i += 256) {
    int r = i >> 6, d = i & 63;
    tbl[r * 65 + d] = tbl_g[i];
  }
  const int w = tid >> 6, lane = tid & 63;
  const int rid = blockIdx.x * 4 + w;
  const int b = rid >> 15, h = (rid >> 11) & 15, q = rid & 2047;
  qsh[w * 64 + lane] =
      qkv[(size_t)(b * 2048 + q) * 3072 + h * 64 + lane];
  __syncthreads();
  float acc = 0.f;
#pragma unroll
  for (int d = 0; d < 64; ++d)
    acc = fmaf(qsh[w * 64 + d], tbl[lane * 65 + d], acc);
  proj[(size_t)rid * 65 + lane] = acc;
  float part = qsh[w * 64 + lane] * tbl[64 * 65 + lane];
#pragma unroll
  for (int off = 32; off; off >>= 1) part += __shfl_xor(part, off, 64);
  if (lane == 0) proj[(size_t)rid * 65 + 64] = part;
}

// ---------------------------------------------------------------------------
// attn_fused v3: single merged QK->PV pass, deferred normalization.
//  - writes UNNORMALIZED p to att; stores inv_denom per row for att_norm.
//  - p for current k-tile lives in wave-local p_s[16][68] (no 128KB buffer).
//  - K/V double-buffered in LDS + 2-deep register prefetch; ONE barrier/tile.
// 512 threads = 8 waves; wave w owns q-rows 2w, 2w+1; lane = k-col / v-dim.
// LDS: 2*(64*68 + 64*64)*4 + 16*68*4 + 16*64*4 + 16*65*4 = ~79.3 KB
//   -> 2 blocks/CU; __launch_bounds__(512,4) caps VGPR at 128 (4 waves/SIMD).
// ---------------------------------------------------------------------------
__global__ __launch_bounds__(512, 4)
void attn_fused(const float* __restrict__ qkv, const float* __restrict__ proj,
                float* __restrict__ att, float* __restrict__ ymid,
                float* __restrict__ dinv) {
  __shared__ float kv_k[2][64 * 68];   // K tiles, [k][d] stride 68
  __shared__ float kv_v[2][64 * 64];   // V tiles, swizzled [d][4*(k4^(d&15))]
  __shared__ float p_s[16 * 68];       // wave-local p for current tile
  __shared__ float qt[16 * 64];
  __shared__ float pj[16 * 65];
  const int tid = threadIdx.x;
  const int w = tid >> 6, lane = tid & 63;
  const int bh = blockIdx.y;               // b*16+h
  const int b = bh >> 4, h = bh & 15;
  const int q0 = blockIdx.x << 4;
  const size_t row_base = (size_t)(b * 2048) * 3072 + h * 64;

  if (tid < 256) {
    int r = tid >> 4, c4 = (tid & 15) << 2;
    *(float4*)&qt[r * 64 + c4] =
        *(const float4*)&qkv[row_base + (size_t)(q0 + r) * 3072 + c4];
  }
  {
    const float* psrc = &proj[((size_t)bh * 2048 + q0) * 65];
    for (int i = tid; i < 16 * 65; i += 512) pj[i] = psrc[i];
  }

  const int r0 = w * 2, r1 = r0 + 1;
  const int qg0 = q0 + r0, qg1 = q0 + r1;
  const int nkt = q0 / 64 + 1;

  const float* kbase = qkv + row_base + 1024;
  const float* vbase = qkv + row_base + 2048;

  // staging indices (per thread, 2 chunks each for K and V)
  const int kk0 = tid >> 4, d40 = (tid & 15) << 2;          // K rows 0..31
  const int kk1 = kk0 + 32;                                  // K rows 32..63
  const int dA = tid & 63, k4A = tid >> 6;                   // V k4 0..7
  const int k4B = k4A + 8;                                   // V k4 8..15

  float4 rk0, rk1, rv0, rv1;  // prefetch registers

#define LOAD_TILE(t)                                                        \
  {                                                                         \
    rk0 = *(const float4*)&kbase[(size_t)((t) * 64 + kk0) * 3072 + d40];    \
    rk1 = *(const float4*)&kbase[(size_t)((t) * 64 + kk1) * 3072 + d40];    \
    const float* s0 = &vbase[(size_t)((t) * 64 + 4 * k4A) * 3072 + dA];     \
    rv0.x = s0[0]; rv0.y = s0[3072]; rv0.z = s0[6144]; rv0.w = s0[9216];    \
    const float* s1 = &vbase[(size_t)((t) * 64 + 4 * k4B) * 3072 + dA];     \
    rv1.x = s1[0]; rv1.y = s1[3072]; rv1.z = s1[6144]; rv1.w = s1[9216];    \
  }
#define STORE_TILE(bi)                                                      \
  {                                                                         \
    *(float4*)&kv_k[bi][kk0 * 68 + d40] = rk0;                              \
    *(float4*)&kv_k[bi][kk1 * 68 + d40] = rk1;                              \
    *(float4*)&kv_v[bi][dA * 64 + 4 * (k4A ^ (dA & 15))] = rv0;             \
    *(float4*)&kv_v[bi][dA * 64 + 4 * (k4B ^ (dA & 15))] = rv1;             \
  }

  // prologue: tile 0 staged, tile 1 in regs
  LOAD_TILE(0);
  STORE_TILE(0);
  if (nkt > 1) LOAD_TILE(1);
  __syncthreads();

  float dacc0 = 0.f, dacc1 = 0.f;
  float y0a = 0.f, y0b = 0.f, y1a = 0.f, y1b = 0.f;
  float* att0 = &att[((size_t)bh * 2048 + qg0) * 2048];
  float* att1 = &att[((size_t)bh * 2048 + qg1) * 2048];

  for (int t = 0; t < nkt; ++t) {
    const int cur = t & 1;
    if (t + 1 < nkt) STORE_TILE(cur ^ 1);   // stage next (other buffer - safe)
    if (t + 2 < nkt) LOAD_TILE(t + 2);      // issue loads; hide under compute

    // ---- QK: lane = k-col; q rows from qt (broadcast b128 reads) ----
    float a0a = 0.f, a0b = 0.f, a1a = 0.f, a1b = 0.f;
#pragma unroll
    for (int c = 0; c < 16; ++c) {
      float4 kv = *(float4*)&kv_k[cur][lane * 68 + 4 * c];
      float4 qa = *(float4*)&qt[r0 * 64 + 4 * c];
      float4 qb = *(float4*)&qt[r1 * 64 + 4 * c];
      a0a = fmaf(qa.x, kv.x, a0a);
      a0b = fmaf(qa.y, kv.y, a0b);
      a0a = fmaf(qa.z, kv.z, a0a);
      a0b = fmaf(qa.w, kv.w, a0b);
      a1a = fmaf(qb.x, kv.x, a1a);
      a1b = fmaf(qb.y, kv.y, a1b);
      a1a = fmaf(qb.z, kv.z, a1a);
      a1b = fmaf(qb.w, kv.w, a1b);
    }
    float acc0 = a0a + a0b, acc1 = a1a + a1b;
    const int kg = t * 64 + lane;
    float p0 = 0.f, p1 = 0.f;
    if (kg <= qg0) {
      int dist = qg0 - kg;
      int idx = 32 - (dist > 32 ? 32 : dist);   // clip(k-q,-32,32)+32
      p0 = __expf((acc0 + pj[r0 * 65 + idx]) * 0.125f);
      dacc0 += p0;
    }
    if (kg <= qg1) {
      int dist = qg1 - kg;
      int idx = 32 - (dist > 32 ? 32 : dist);
      p1 = __expf((acc1 + pj[r1 * 65 + idx]) * 0.125f);
      dacc1 += p1;
    }
    // wave-local p stash (same wave writes & reads: no barrier needed)
    p_s[r0 * 68 + lane] = p0;
    p_s[r1 * 68 + lane] = p1;
    // unnormalized att out (normalized later by att_norm)
    att0[t * 64 + lane] = p0;
    att1[t * 64 + lane] = p1;

    // ---- PV: lane = v-dim d ----
#pragma unroll
    for (int c = 0; c < 16; ++c) {
      float4 vv = *(float4*)&kv_v[cur][lane * 64 + 4 * (c ^ (lane & 15))];
      float4 pb0 = *(float4*)&p_s[r0 * 68 + 4 * c];
      float4 pb1 = *(float4*)&p_s[r1 * 68 + 4 * c];
      y0a = fmaf(pb0.x, vv.x, y0a);
      y0b = fmaf(pb0.y, vv.y, y0b);
      y0a = fmaf(pb0.z, vv.z, y0a);
      y0b = fmaf(pb0.w, vv.w, y0b);
      y1a = fmaf(pb1.x, vv.x, y1a);
      y1b = fmaf(pb1.y, vv.y, y1b);
      y1a = fmaf(pb1.z, vv.z, y1a);
      y1b = fmaf(pb1.w, vv.w, y1b);
    }
    __syncthreads();  // all waves done with buffers before next stage
  }
#undef LOAD_TILE
#undef STORE_TILE

#pragma unroll
  for (int off = 32; off; off >>= 1) {
    dacc0 += __shfl_xor(dacc0, off, 64);
    dacc1 += __shfl_xor(dacc1, off, 64);
  }
  const float inv0 = 1.f / dacc0, inv1 = 1.f / dacc1;
  if (lane == 0) {
    dinv[(size_t)bh * 2048 + qg0] = inv0;
    dinv[(size_t)bh * 2048 + qg1] = inv1;
  }
  ymid[(size_t)(b * 2048 + qg0) * 1024 + h * 64 + lane] = (y0a + y0b) * inv0;
  ymid[(size_t)(b * 2048 + qg1) * 1024 + h * 64 + lane] = (y1a + y1b) * inv1;
}

// ---------------------------------------------------------------------------
// att_norm: att[row][k] = k<=q ? att[row][k]*dinv[row] : 0
// one block per row (row = bh*2048+q), 256 threads x 8 elems.
// ---------------------------------------------------------------------------
__global__ __launch_bounds__(256)
void att_norm(float* __restrict__ att, const float* __restrict__ dinv) {
  const size_t row = blockIdx.x;
  const int q = (int)(row & 2047);
  const float inv = dinv[row];
  float* p = att + row * 2048;
  const int c0 = threadIdx.x * 8;
  if (c0 + 7 <= q) {
    float4 a = *(float4*)&p[c0];
    float4 c = *(float4*)&p[c0 + 4];
    a.x *= inv; a.y *= inv; a.z *= inv; a.w *= inv;
    c.x *= inv; c.y *= inv; c.z *= inv; c.w *= inv;
    *(float4*)&p[c0] = a;
    *(float4*)&p[c0 + 4] = c;
  } else if (c0 > q) {
    float4 z = {0.f, 0.f, 0.f, 0.f};
    *(float4*)&p[c0] = z;
    *(float4*)&p[c0 + 4] = z;
  } else {
    float4 a, c;
    a.x = (c0 + 0 <= q) ? p[c0 + 0] * inv : 0.f;
    a.y = (c0 + 1 <= q) ? p[c0 + 1] * inv : 0.f;
    a.z = (c0 + 2 <= q) ? p[c0 + 2] * inv : 0.f;
    a.w = (c0 + 3 <= q) ? p[c0 + 3] * inv : 0.f;
    c.x = (c0 + 4 <= q) ? p[c0 + 4] * inv : 0.f;
    c.y = (c0 + 5 <= q) ? p[c0 + 5] * inv : 0.f;
    c.z = (c0 + 6 <= q) ? p[c0 + 6] * inv : 0.f;
    c.w = (c0 + 7 <= q) ? p[c0 + 7] * inv : 0.f;
    *(float4*)&p[c0] = a;
    *(float4*)&p[c0 + 4] = c;
  }
}

// ---------------------------------------------------------------------------
extern "C" void kernel_launch(void* const* d_in, const int* in_sizes, int n_in,
                              void* d_out, int out_size, void* d_ws, size_t ws_size,
                              hipStream_t stream) {
  const float* x       = (const float*)d_in[0];
  // d_in[1] = mask (causal tril) -- structure known, unused
  const float* w_attn  = (const float*)d_in[2];
  const float* b_attn  = (const float*)d_in[3];
  const float* w_proj  = (const float*)d_in[4];
  const float* b_proj  = (const float*)d_in[5];
  const float* rel_tbl = (const float*)d_in[6];

  float* out = (float*)d_out;
  float* att = out + (size_t)2 * 2048 * 1024;          // y first, then att

  // workspace layout (~118 MB, same footprint as round 6)
  float* qkv  = (float*)d_ws;                          // 12,582,912 f32
  float* proj = qkv + (size_t)12582912;                // 4,259,840 f32
  float* ymid = proj + (size_t)4259840;                // 4,194,304 f32
  unsigned short* xh  = (unsigned short*)(ymid + (size_t)4194304);
  unsigned short* xl  = xh + (size_t)4194304;
  unsigned short* wah = xl + (size_t)4194304;
  unsigned short* wal = wah + (size_t)3145728;
  unsigned short* wph = wal + (size_t)3145728;
  unsigned short* wpl = wph + (size_t)1048576;
  // dinv (65536 f32) aliases wah: wah is dead after the qkv GEMM, and is
  // rewritten by cvt_split_T at the start of every call.
  float* dinv = (float*)wah;

  // 0) split-precision conversions
  cvt_split<<<4096, 256, 0, stream>>>(x, xh, xl, 1048576);
  cvt_split_T<<<dim3(48, 16), 256, 0, stream>>>(w_attn, wah, wal, 1024, 3072);
  cvt_split_T<<<dim3(16, 16), 256, 0, stream>>>(w_proj, wph, wpl, 1024, 1024);

  // 1) qkv = x @ w_attn + b_attn   (split-bf16 MFMA)
  mfma_gemm_bias<<<dim3(24, 32), 256, 0, stream>>>(xh, xl, wah, wal, b_attn,
                                                   qkv, 4096, 3072, 1024);
  // 2) rel-position projection
  relproj_kernel<<<16384, 256, 0, stream>>>(qkv, rel_tbl, proj);
  // 3) fused attention: unnormalized att + dinv + normalized y
  attn_fused<<<dim3(128, 32), 512, 0, stream>>>(qkv, proj, att, ymid, dinv);
  // 3b) normalize att rows + zero-fill masked region
  att_norm<<<65536, 256, 0, stream>>>(att, dinv);
  // 4) out = ymid @ w_proj + b_proj   (split-bf16 MFMA)
  cvt_split<<<4096, 256, 0, stream>>>(ymid, xh, xl, 1048576);
  mfma_gemm_bias<<<dim3(8, 32), 256, 0, stream>>>(xh, xl, wph, wpl, b_proj,
                                                  out, 4096, 1024, 1024);
}